// Round 1
// baseline (2898.603 us; speedup 1.0000x reference)
//
#include <hip/hip_runtime.h>
#include <hip/hip_bf16.h>

// CharNNClassifier: out = (LSTM(emb[x]) last h) @ W_out^T + b_out
// B=256 S=512 V=256 E=128 H=256 4H=1024 O=128, all fp32 in/out.
//
// Plan:
//  K1 build_table: T[v][g] = W_ih @ emb[v] + b_ih + b_hh   (V=256 x 1024 fp32)
//                  (also zeroes the per-step sync flags in ws)
//  K2 lstm_persistent: 64 wgs = 16 batch-stripes x 4 hidden-quarters.
//     Each wg holds its quarter of W_hh in VGPRs as split-bf16 (hi+lo)
//     MFMA B-fragments (256 VGPR/lane; 4 waves => 1 wave/SIMD => 512 budget).
//     Per step: gates[16,256] = h[16,256] @ Wq^T via 2x mfma_f32_16x16x32_bf16
//     (hi+lo), + T gather (fp32), nonlinearities in fp32, c in fp32 regs,
//     h -> bf16 published via AGENT-scope atomics (cross-XCD correct),
//     4-way flag sync per (step,stripe). h double-buffered by step parity.
//  K3 out_kernel: out[256,128] = h_last @ W_out^T + b_out (fp32).

typedef __bf16 bf16x8 __attribute__((ext_vector_type(8)));
typedef float  f32x4  __attribute__((ext_vector_type(4)));

#define B_  256
#define S_  512
#define V_  256
#define E_  128
#define H_  256
#define G4_ 1024
#define O_  128

// ws layout (bytes)
#define T_OFF     0u                         // 256*1024*4 = 1 MiB
#define HEX_OFF   (1u << 20)                 // 2 * 256*256 * 2B = 256 KiB (dbuf)
#define HLAST_OFF (HEX_OFF + 2u*256u*256u*2u)  // 256*256*4 = 256 KiB
#define FLAG_OFF  (HLAST_OFF + 256u*256u*4u)   // 512*16*4 = 32 KiB
#define HEX_U64_PER_BUF (256u*256u/4u)       // 16384 u64 per buffer

// ---------------------------------------------------------------- K1: table
__global__ void build_table(const float* __restrict__ emb,
                            const float* __restrict__ W_ih,
                            const float* __restrict__ b_ih,
                            const float* __restrict__ b_hh,
                            float* __restrict__ T,
                            int* __restrict__ flags) {
    const int v   = blockIdx.x;   // vocab id
    const int tid = threadIdx.x;  // 256 threads

    // zero the 8192 sync flags (512 steps x 16 stripes) across 256 blocks
    if (tid < 32) flags[v * 32 + tid] = 0;

    __shared__ float e[E_];
    if (tid < E_) e[tid] = emb[v * E_ + tid];
    __syncthreads();

#pragma unroll
    for (int p = 0; p < 4; ++p) {
        const int g = p * 256 + tid;
        const float4* wp = (const float4*)(W_ih + g * E_);
        float acc = 0.f;
#pragma unroll
        for (int i = 0; i < E_ / 4; ++i) {
            float4 w = wp[i];
            acc += w.x * e[4*i] + w.y * e[4*i+1] + w.z * e[4*i+2] + w.w * e[4*i+3];
        }
        T[v * G4_ + g] = acc + b_ih[g] + b_hh[g];
    }
}

// ------------------------------------------------------------ K2: recurrence
__device__ __forceinline__ float sig_fast(float x) {
    x = fminf(fmaxf(x, -30.f), 30.f);
    float t = __builtin_amdgcn_exp2f(-1.4426950408889634f * x);
    return __builtin_amdgcn_rcpf(1.f + t);
}
__device__ __forceinline__ float tanh_fast(float x) {
    x = fminf(fmaxf(x, -15.f), 15.f);
    float t = __builtin_amdgcn_exp2f(-2.8853900817779268f * x);  // e^{-2x}
    return (1.f - t) * __builtin_amdgcn_rcpf(1.f + t);
}

__launch_bounds__(256, 1)
__global__ void lstm_persistent(const int* __restrict__ x,
                                const float* __restrict__ W_hh,
                                const float* __restrict__ T,
                                unsigned long long* __restrict__ hex,
                                float* __restrict__ hlast,
                                int* __restrict__ flags) {
    const int tid  = threadIdx.x;
    const int wv   = tid >> 6;        // wave 0..3
    const int l    = tid & 63;
    const int l15  = l & 15;
    const int quad = l >> 4;          // 0..3
    // partner wgs of a stripe = {stripe, 16+stripe, 32+stripe, 48+stripe}
    // -> same XCD under round-robin dispatch (locality heuristic only).
    const int q      = blockIdx.x >> 4;   // hidden quarter 0..3
    const int stripe = blockIdx.x & 15;   // batch stripe 0..15
    const int unit   = q * 64 + wv * 16 + l15;   // hidden unit (B-frag n / C col)

    // ---- prologue: W_hh quarter -> split-bf16 MFMA B-fragments in VGPRs.
    // B-frag (16x16x32): lane holds B[k = quad*8 + j][n = l15], k contiguous 8.
    // C[m=batch,n=gate] = sum_k h[m,k]*W_hh[gate,k]  => B[k][n] = W_hh[gate_n][k].
    bf16x8 whi[4][8], wlo[4][8];
#pragma unroll
    for (int t = 0; t < 4; ++t) {               // gate type i,f,g,o
        const int grow = t * H_ + unit;         // W_hh row
#pragma unroll
        for (int kt = 0; kt < 8; ++kt) {        // K tiles of 32
            const float* wp = W_hh + grow * H_ + kt * 32 + quad * 8;
#pragma unroll
            for (int j = 0; j < 8; ++j) {
                float w  = wp[j];
                __bf16 hi = (__bf16)w;
                __bf16 lo = (__bf16)(w - (float)hi);
                whi[t][kt][j] = hi;
                wlo[t][kt][j] = lo;
            }
        }
    }

    // C/D layout: col = l15 (unit), row = quad*4 + r  (verified m89/m91)
    int rows[4];
#pragma unroll
    for (int r = 0; r < 4; ++r) rows[r] = stripe * 16 + quad * 4 + r;

    float c[4] = {0.f, 0.f, 0.f, 0.f};

    // per-wave 16x16 bf16 transpose tile for packing h into 8B atomic stores
    __shared__ __align__(16) unsigned short hts[4][16][16];

    for (int s = 0; s < S_; ++s) {
        f32x4 acc[4];
#pragma unroll
        for (int t = 0; t < 4; ++t) acc[t] = (f32x4){0.f, 0.f, 0.f, 0.f};

        if (s > 0) {
            // wait for all 4 partners to have published h_s
            if (tid == 0) {
                while (__hip_atomic_load(&flags[(s - 1) * 16 + stripe],
                                         __ATOMIC_RELAXED,
                                         __HIP_MEMORY_SCOPE_AGENT) < 4) { }
            }
            __syncthreads();

            // A-frags: lane holds A[m = l15][k = quad*8 + j]; read h via
            // AGENT atomic loads (coherent across XCDs, no cache staleness).
            const unsigned long long* hb =
                hex + (size_t)((s - 1) & 1) * HEX_U64_PER_BUF;
            bf16x8 a[8];
#pragma unroll
            for (int kt = 0; kt < 8; ++kt) {
                const int grow = stripe * 16 + l15;          // batch row
                const int k0   = kt * 32 + quad * 8;         // hidden k
                const size_t idx = ((size_t)grow * 256 + k0) >> 2;  // u64 index
                unsigned long long u0 = __hip_atomic_load(
                    hb + idx, __ATOMIC_RELAXED, __HIP_MEMORY_SCOPE_AGENT);
                unsigned long long u1 = __hip_atomic_load(
                    hb + idx + 1, __ATOMIC_RELAXED, __HIP_MEMORY_SCOPE_AGENT);
                union { unsigned long long u[2]; bf16x8 v; } cv;
                cv.u[0] = u0; cv.u[1] = u1;
                a[kt] = cv.v;
            }
            // gates += (W_hi + W_lo) @ h   (split-bf16 ~= fp32 weights)
#pragma unroll
            for (int t = 0; t < 4; ++t) {
#pragma unroll
                for (int kt = 0; kt < 8; ++kt) {
                    acc[t] = __builtin_amdgcn_mfma_f32_16x16x32_bf16(
                        a[kt], whi[t][kt], acc[t], 0, 0, 0);
                    acc[t] = __builtin_amdgcn_mfma_f32_16x16x32_bf16(
                        a[kt], wlo[t][kt], acc[t], 0, 0, 0);
                }
            }
        }

        // input contribution: fp32 gather from T (exact)
#pragma unroll
        for (int r = 0; r < 4; ++r) {
            const int vv = x[rows[r] * S_ + s];
#pragma unroll
            for (int t = 0; t < 4; ++t)
                acc[t][r] += T[vv * G4_ + t * H_ + unit];
        }

        // gate nonlinearities + state update (fp32, c stays in regs)
        float hval[4];
#pragma unroll
        for (int r = 0; r < 4; ++r) {
            float ig = sig_fast(acc[0][r]);
            float fg = sig_fast(acc[1][r]);
            float gg = tanh_fast(acc[2][r]);
            float og = sig_fast(acc[3][r]);
            c[r]    = fg * c[r] + ig * gg;
            hval[r] = og * tanh_fast(c[r]);
        }

        if (s < S_ - 1) {
            // transpose via LDS so each lane stores one aligned 8B chunk
#pragma unroll
            for (int r = 0; r < 4; ++r) {
                union { __bf16 b; unsigned short u; } cv;
                cv.b = (__bf16)hval[r];
                hts[wv][quad * 4 + r][l15] = cv.u;
            }
            __syncthreads();
            const int prow = l >> 2;
            const int pcg  = (l & 3) * 4;
            unsigned long long pk =
                *(const unsigned long long*)&hts[wv][prow][pcg];
            unsigned long long* hbw = hex + (size_t)(s & 1) * HEX_U64_PER_BUF;
            const size_t didx =
                ((size_t)(stripe * 16 + prow) * 256 + q * 64 + wv * 16 + pcg) >> 2;
            __hip_atomic_store(hbw + didx, pk, __ATOMIC_RELAXED,
                               __HIP_MEMORY_SCOPE_AGENT);
            __syncthreads();  // all wg stores issued & drained (barrier waits vmcnt)
            if (tid == 0)
                __hip_atomic_fetch_add(&flags[s * 16 + stripe], 1,
                                       __ATOMIC_RELEASE,
                                       __HIP_MEMORY_SCOPE_AGENT);
        } else {
            // final h in fp32 for the output head (kernel boundary = coherent)
#pragma unroll
            for (int r = 0; r < 4; ++r)
                hlast[rows[r] * H_ + unit] = hval[r];
        }
    }
}

// ---------------------------------------------------------------- K3: head
__global__ void out_kernel(const float* __restrict__ hlast,
                           const float* __restrict__ W_out,
                           const float* __restrict__ b_out,
                           float* __restrict__ out) {
    const int b = blockIdx.x;    // 256
    const int o = threadIdx.x;   // 128
    __shared__ float hl[H_];
    hl[o]       = hlast[b * H_ + o];
    hl[o + 128] = hlast[b * H_ + o + 128];
    __syncthreads();
    const float4* wp = (const float4*)(W_out + o * H_);
    float acc = 0.f;
#pragma unroll
    for (int i = 0; i < H_ / 4; ++i) {
        float4 w = wp[i];
        acc += w.x * hl[4*i] + w.y * hl[4*i+1] + w.z * hl[4*i+2] + w.w * hl[4*i+3];
    }
    out[b * O_ + o] = acc + b_out[o];
}

// ----------------------------------------------------------------- launcher
extern "C" void kernel_launch(void* const* d_in, const int* in_sizes, int n_in,
                              void* d_out, int out_size, void* d_ws, size_t ws_size,
                              hipStream_t stream) {
    const int*   x     = (const int*)  d_in[0];
    const float* emb   = (const float*)d_in[1];
    const float* W_ih  = (const float*)d_in[2];
    const float* W_hh  = (const float*)d_in[3];
    const float* b_ih  = (const float*)d_in[4];
    const float* b_hh  = (const float*)d_in[5];
    const float* W_out = (const float*)d_in[6];
    const float* b_out = (const float*)d_in[7];
    float* out = (float*)d_out;

    char* ws = (char*)d_ws;
    float*              T     = (float*)(ws + T_OFF);
    unsigned long long* hex   = (unsigned long long*)(ws + HEX_OFF);
    float*              hlast = (float*)(ws + HLAST_OFF);
    int*                flags = (int*)(ws + FLAG_OFF);

    build_table<<<dim3(V_), dim3(256), 0, stream>>>(emb, W_ih, b_ih, b_hh, T, flags);
    lstm_persistent<<<dim3(64), dim3(256), 0, stream>>>(x, W_hh, T, hex, hlast, flags);
    out_kernel<<<dim3(B_), dim3(O_), 0, stream>>>(hlast, W_out, b_out, out);
}